// Round 7
// baseline (1030.372 us; speedup 1.0000x reference)
//
#include <hip/hip_runtime.h>
#include <cmath>

typedef __attribute__((ext_vector_type(8))) short short8;
typedef __attribute__((ext_vector_type(4))) float f32x4;

#define B_   32
#define C_   64
#define T_   8192
#define H_   256
#define TT   64
#define NSUB 4               // t-tiles per block (A-fragment L2 traffic / NSUB)

// LDS geometry (bytes). Row r of rs1 <-> time t0-18+r; row r of rs2 <-> t0-2+r.
#define XS_ROWB 144          // 64ch*2B + 16B pad
#define RS_ROWB 528          // 256ch*2B + 16B pad (132 floats)
#define RS1_OFF 0            // 82 rows * 528 = 43296
#define RS2_OFF 43296        // 66 rows * 528 = 34848
#define XS_OFF  43296        // xs [83 rows][144B] aliases rs2 (disjoint lifetimes)
#define RS3_OFF 0            // rs3 fp32 [64 rows][528B] aliases rs1 (dead after conv2)
#define LDS_BYTES 78144      // 2 blocks/CU

// packed-A workspace (bytes): frag = ((tap*MT + mt)*KT + ck) * 1024
#define A1_SZ 98304          // 3*16*2 frags
#define A2_SZ 393216         // 3*16*8
#define A3_SZ 196608         // 3*8*8
#define AW_TOTAL (A1_SZ + A2_SZ + A3_SZ)

__device__ __forceinline__ unsigned short f2bf(float f) {
    unsigned u = __builtin_bit_cast(unsigned, f);
    u += 0x7fffu + ((u >> 16) & 1u);          // RNE
    return (unsigned short)(u >> 16);
}

// HW packed f32->bf16 (RNE): low16 = bf16(lo), high16 = bf16(hi)
__device__ __forceinline__ unsigned cvtpk(float lo, float hi) {
    unsigned r;
    asm("v_cvt_pk_bf16_f32 %0, %1, %2" : "=v"(r) : "v"(lo), "v"(hi));
    return r;
}

// ---- pack fp32 weights -> bf16 MFMA A-fragments in d_ws ----
__global__ void pack_w(const float* __restrict__ w1, const float* __restrict__ w2,
                       const float* __restrict__ w3, unsigned short* __restrict__ ws)
{
    int id = blockIdx.x * 256 + threadIdx.x;          // frag-lane id, 43008 total
    const float* w; int MT, KT, Cin; unsigned short* dst;
    if (id < 6144)       {             w = w1; MT = 16; KT = 2; Cin = 64;  dst = ws; }
    else if (id < 30720) { id -= 6144; w = w2; MT = 16; KT = 8; Cin = 256; dst = ws + A1_SZ/2; }
    else if (id < 43008) { id -= 30720; w = w3; MT = 8; KT = 8; Cin = 256; dst = ws + (A1_SZ+A2_SZ)/2; }
    else return;
    const int lane = id & 63;
    int f = id >> 6;
    const int kt = f % KT; f /= KT;
    const int mt = f % MT;
    const int tap = f / MT;
    const int h  = mt*16 + (lane & 15);               // A row (out-channel)
    const int c0 = kt*32 + (lane >> 4)*8;             // A k (in-channel), 8 consecutive
    unsigned short* o = dst + (size_t)id * 8;
    #pragma unroll
    for (int j = 0; j < 8; ++j)
        o[j] = f2bf(w[((size_t)(h*Cin + c0 + j))*3 + tap]);
}

__device__ __forceinline__ short8 ldA(const char* base, int frag, int lane) {
    return *(const short8*)(base + ((size_t)frag*64 + lane)*16);
}

__global__ __launch_bounds__(512, 4)
void arflow_mfma(const float* __restrict__ x,
                 const float* __restrict__ b_in, const float* __restrict__ b_mid,
                 const float* __restrict__ b_out,
                 const float* __restrict__ alpha, const float* __restrict__ beta,
                 const char* __restrict__ wpk,
                 float* __restrict__ out)
{
    __shared__ __align__(16) char lds[LDS_BYTES];
    unsigned short* xs = (unsigned short*)(lds + XS_OFF);   // [83 rows][72 ushort], row r <-> t0-19+r
    char* rs1 = lds + RS1_OFF;
    char* rs2 = lds + RS2_OFF;

    const char* wA1 = wpk;
    const char* wA2 = wpk + A1_SZ;
    const char* wA3 = wpk + A1_SZ + A2_SZ;

    const int b   = blockIdx.y;
    const int t00 = blockIdx.x * (TT * NSUB);
    const int tid = threadIdx.x;
    const int lane = tid & 63;
    const int wid  = tid >> 6;
    const int l15 = lane & 15, l4 = lane >> 4;

    #pragma unroll 1
    for (int s = 0; s < NSUB; ++s) {
        const int t0 = t00 + s * TT;

        // ---------------- stage x -> xs bf16; zero rs1 halo rows 0,1 ----------------
        {
            const int rr = tid & 63, cg = tid >> 6;
            #pragma unroll
            for (int p = 0; p < 4; ++p) {
                const int c = cg*8 + p*2;
                const float* xc0 = x + ((size_t)b*C_ + c)*T_;
                const float* xc1 = xc0 + T_;
                {
                    const int t = t0 - 19 + rr;
                    float v0 = 0.f, v1 = 0.f;
                    if (t >= 0) { v0 = xc0[t]; v1 = xc1[t]; }
                    *(unsigned*)(&xs[rr*72 + c]) = cvtpk(v0, v1);
                }
                {
                    const int r = rr + 64;
                    if (r < 83) {
                        const int t = t0 - 19 + r;   // always in [45, 8191]
                        *(unsigned*)(&xs[r*72 + c]) = cvtpk(xc0[t], xc1[t]);
                    }
                }
            }
            if (tid < 264) ((unsigned*)rs1)[tid] = 0u;   // rows 0,1 (t0-18,t0-17) = 0
        }
        __syncthreads();

        // ---- conv1: xs(64) -> rs1(256). Wave wid: mtiles {2wid,2wid+1} x all 5 ntiles.
        //      A1 x1 per sub-tile. K=6 (3 taps x 2 ck) ----
        {
            const int mt0 = wid*2;
            f32x4 acc[2][5];
            #pragma unroll
            for (int m = 0; m < 2; ++m) {
                const f32x4 bv = *(const f32x4*)(b_in + (mt0+m)*16 + l4*4);
                #pragma unroll
                for (int nt = 0; nt < 5; ++nt) acc[m][nt] = bv;
            }
            int nb[5];
            #pragma unroll
            for (int nt = 0; nt < 5; ++nt)
                nb[nt] = XS_OFF + (16*nt + l15)*XS_ROWB + l4*16;
            short8 Ab[2][2];
            #pragma unroll
            for (int m = 0; m < 2; ++m) Ab[0][m] = ldA(wA1, (mt0+m)*2, lane);
            #pragma unroll
            for (int kt = 0; kt < 6; ++kt) {
                const int cur = kt & 1;
                const int tap = kt >> 1, ck = kt & 1;
                if (kt < 5) {
                    const int kn = kt+1, tapn = kn>>1, ckn = kn&1;
                    #pragma unroll
                    for (int m = 0; m < 2; ++m)
                        Ab[cur^1][m] = ldA(wA1, (tapn*16 + mt0+m)*2 + ckn, lane);
                }
                __builtin_amdgcn_s_setprio(1);
                #pragma unroll
                for (int nt = 0; nt < 5; ++nt) {
                    const short8 Bf = *(const short8*)(lds + nb[nt] + tap*XS_ROWB + ck*64);
                    #pragma unroll
                    for (int m = 0; m < 2; ++m)
                        acc[m][nt] = __builtin_amdgcn_mfma_f32_16x16x32_bf16(Ab[cur][m], Bf, acc[m][nt], 0, 0, 0);
                }
                __builtin_amdgcn_s_setprio(0);
            }
            #pragma unroll
            for (int nt = 0; nt < 5; ++nt) {
                const int tt16 = 16*nt + l15;
                const int t = t0 - 16 + tt16;
                char* dst0 = rs1 + (2 + tt16)*RS_ROWB;
                #pragma unroll
                for (int m = 0; m < 2; ++m) {
                    const f32x4 a = acc[m][nt];
                    unsigned long long pk = 0ull;
                    if (t >= 0)
                        pk = (unsigned long long)cvtpk(a.x, a.y)
                           | ((unsigned long long)cvtpk(a.z, a.w) << 32);
                    *(unsigned long long*)(dst0 + ((mt0+m)*16 + l4*4)*2) = pk;
                }
            }
        }
        __syncthreads();

        // ---- conv2: rs1(256) -> rs2(256). Wm=4/Wn=2 (balanced). K=24 ----
        {
            const int mg = wid >> 1, ng = wid & 1;
            const int ntb = ng ? 3 : 0, ncnt = ng ? 2 : 3;
            f32x4 acc[4][3];
            #pragma unroll
            for (int m = 0; m < 4; ++m) {
                const f32x4 bv = *(const f32x4*)(b_mid + (mg*4+m)*16 + l4*4);
                #pragma unroll
                for (int nt = 0; nt < 3; ++nt) acc[m][nt] = bv;
            }
            int nb[3];
            #pragma unroll
            for (int nt = 0; nt < 3; ++nt)
                nb[nt] = RS1_OFF + (16*(ntb+nt) + l15)*RS_ROWB + l4*16;
            short8 Ab[2][4];
            #pragma unroll
            for (int m = 0; m < 4; ++m) Ab[0][m] = ldA(wA2, (mg*4+m)*8, lane);
            #pragma unroll
            for (int kt = 0; kt < 24; ++kt) {
                const int cur = kt & 1;
                const int tap = kt >> 3, ck = kt & 7;
                if (kt < 23) {
                    const int kn = kt+1, tapn = kn>>3, ckn = kn&7;
                    #pragma unroll
                    for (int m = 0; m < 4; ++m)
                        Ab[cur^1][m] = ldA(wA2, (tapn*16 + mg*4+m)*8 + ckn, lane);
                }
                __builtin_amdgcn_s_setprio(1);
                #pragma unroll
                for (int nt = 0; nt < 3; ++nt) if (nt < ncnt) {
                    const short8 Bf = *(const short8*)(lds + nb[nt] + tap*RS_ROWB + ck*64);
                    #pragma unroll
                    for (int m = 0; m < 4; ++m)
                        acc[m][nt] = __builtin_amdgcn_mfma_f32_16x16x32_bf16(Ab[cur][m], Bf, acc[m][nt], 0, 0, 0);
                }
                __builtin_amdgcn_s_setprio(0);
            }
            #pragma unroll
            for (int nt = 0; nt < 3; ++nt) if (nt < ncnt) {
                const int tt16 = 16*(ntb+nt) + l15;
                const int r2row = tt16 - 14;             // rs2 row <-> t0-2+row
                if (r2row >= 0) {
                    const int t = t0 - 16 + tt16;
                    char* dst0 = rs2 + r2row*RS_ROWB;
                    #pragma unroll
                    for (int m = 0; m < 4; ++m) {
                        const f32x4 a = acc[m][nt];
                        unsigned long long pk = 0ull;
                        if (t >= 0)
                            pk = (unsigned long long)cvtpk(a.x, a.y)
                               | ((unsigned long long)cvtpk(a.z, a.w) << 32);
                        *(unsigned long long*)(dst0 + ((mg*4+m)*16 + l4*4)*2) = pk;
                    }
                }
            }
        }
        __syncthreads();

        // ---- prefetch epilogue x into regs (global, no LDS dep; hides under conv3) ----
        float xv[8];
        {
            #pragma unroll
            for (int m = 0; m < 8; ++m) {
                const int e = tid + m*512;               // 4096 = 64c * 64t
                const int c = e >> 6, tl = e & 63;
                xv[m] = x[((size_t)b*C_ + c)*T_ + t0 + tl];
            }
        }

        // ---- conv3: rs2(256) -> rs3(128, fp32). Wave wid owns mtile wid x ALL 4 ntiles.
        //      A3 x1 per sub-tile. 2-deep A prefetch ----
        {
            const int mt = wid;                          // 0..7 (M=128)
            f32x4 acc[4];
            {
                const f32x4 bv = *(const f32x4*)(b_out + mt*16 + l4*4);
                #pragma unroll
                for (int nt = 0; nt < 4; ++nt) acc[nt] = bv;
            }
            int nb[4];
            #pragma unroll
            for (int nt = 0; nt < 4; ++nt)
                nb[nt] = RS2_OFF + (16*nt + l15)*RS_ROWB + l4*16;
            short8 Ab[2];
            Ab[0] = ldA(wA3, mt*8 + 0, lane);            // kt=0: tap0,ck0
            Ab[1] = ldA(wA3, mt*8 + 1, lane);            // kt=1: tap0,ck1
            #pragma unroll
            for (int kt = 0; kt < 24; ++kt) {
                const int cur = kt & 1;
                const int tap = kt >> 3, ck = kt & 7;
                __builtin_amdgcn_s_setprio(1);
                #pragma unroll
                for (int nt = 0; nt < 4; ++nt) {
                    const short8 Bf = *(const short8*)(lds + nb[nt] + tap*RS_ROWB + ck*64);
                    acc[nt] = __builtin_amdgcn_mfma_f32_16x16x32_bf16(Ab[cur], Bf, acc[nt], 0, 0, 0);
                }
                __builtin_amdgcn_s_setprio(0);
                if (kt + 2 < 24) {
                    const int kn = kt+2, tapn = kn>>3, ckn = kn&7;
                    Ab[cur] = ldA(wA3, (tapn*8 + mt)*8 + ckn, lane);
                }
            }
            #pragma unroll
            for (int nt = 0; nt < 4; ++nt) {
                char* dst0 = lds + RS3_OFF + (16*nt + l15)*RS_ROWB;   // fp32 rows [64][132f]
                *(f32x4*)(dst0 + (mt*16 + l4*4)*4) = acc[nt];
            }
        }
        __syncthreads();

        // ---- epilogue: z = exp(alpha*tanh(log_s)+beta)*x + t ----
        {
            const float* rs3f = (const float*)(lds + RS3_OFF);
            #pragma unroll
            for (int m = 0; m < 8; ++m) {
                const int e = tid + m*512;
                const int c = e >> 6, tl = e & 63;
                const float ls = rs3f[tl*132 + c];
                const float tv = rs3f[tl*132 + c + 64];
                // tanh(ls) = 1 - 2/(exp(2*ls)+1)
                const float e2 = __expf(2.f * ls);
                const float th = fmaf(-2.f, __builtin_amdgcn_rcpf(e2 + 1.f), 1.f);
                const float lsv = fmaf(alpha[c], th, beta[c]);
                out[((size_t)b*C_ + c)*T_ + t0 + tl] = fmaf(__expf(lsv), xv[m], tv);
            }
        }
        __syncthreads();   // WAR: next stage zeroes rs1 rows 0,1 / writes xs
    }
}

extern "C" void kernel_launch(void* const* d_in, const int* in_sizes, int n_in,
                              void* d_out, int out_size, void* d_ws, size_t ws_size,
                              hipStream_t stream) {
    const float* x     = (const float*)d_in[0];
    const float* w_in  = (const float*)d_in[1];
    const float* b_in  = (const float*)d_in[2];
    const float* w_mid = (const float*)d_in[3];
    const float* b_mid = (const float*)d_in[4];
    const float* w_out = (const float*)d_in[5];
    const float* b_out = (const float*)d_in[6];
    const float* alpha = (const float*)d_in[7];
    const float* beta  = (const float*)d_in[8];
    float* out = (float*)d_out;

    if (ws_size < (size_t)AW_TOTAL) return;

    hipLaunchKernelGGL(pack_w, dim3(168), dim3(256), 0, stream,
                       w_in, w_mid, w_out, (unsigned short*)d_ws);
    hipLaunchKernelGGL(arflow_mfma, dim3(T_/(TT*NSUB), B_), dim3(512), 0, stream,
                       x, b_in, b_mid, b_out, alpha, beta, (const char*)d_ws, out);
}

// Round 8
// 703.237 us; speedup vs baseline: 1.4652x; 1.4652x over previous
//
#include <hip/hip_runtime.h>
#include <cmath>

typedef __attribute__((ext_vector_type(8))) short short8;
typedef __attribute__((ext_vector_type(4))) float f32x4;

#define B_   32
#define C_   64
#define T_   8192
#define H_   256
#define TT   64
#define NSUB 2               // t-tiles per block, fully inlined calls (NO loop: reg-spill hazard)

// LDS geometry (bytes). Row r of rs1 <-> time t0-18+r; row r of rs2 <-> t0-2+r.
#define XS_ROWB 144          // 64ch*2B + 16B pad
#define RS_ROWB 528          // 256ch*2B + 16B pad (132 floats)
#define RS1_OFF 0            // 82 rows * 528 = 43296
#define RS2_OFF 43296        // 66 rows * 528 = 34848
#define XS_OFF  43296        // xs [83 rows][144B] aliases rs2 (disjoint lifetimes)
#define RS3_OFF 0            // rs3 fp32 [64 rows][528B] aliases rs1 (dead after conv2)
#define LDS_BYTES 78144      // 2 blocks/CU

// packed-A workspace (bytes): frag = ((tap*MT + mt)*KT + ck) * 1024
#define A1_SZ 98304          // 3*16*2 frags
#define A2_SZ 393216         // 3*16*8
#define A3_SZ 196608         // 3*8*8
#define AW_TOTAL (A1_SZ + A2_SZ + A3_SZ)

__device__ __forceinline__ unsigned short f2bf(float f) {
    unsigned u = __builtin_bit_cast(unsigned, f);
    u += 0x7fffu + ((u >> 16) & 1u);          // RNE
    return (unsigned short)(u >> 16);
}

// HW packed f32->bf16 (RNE): low16 = bf16(lo), high16 = bf16(hi)
__device__ __forceinline__ unsigned cvtpk(float lo, float hi) {
    unsigned r;
    asm("v_cvt_pk_bf16_f32 %0, %1, %2" : "=v"(r) : "v"(lo), "v"(hi));
    return r;
}

// ---- pack fp32 weights -> bf16 MFMA A-fragments in d_ws ----
__global__ void pack_w(const float* __restrict__ w1, const float* __restrict__ w2,
                       const float* __restrict__ w3, unsigned short* __restrict__ ws)
{
    int id = blockIdx.x * 256 + threadIdx.x;          // frag-lane id, 43008 total
    const float* w; int MT, KT, Cin; unsigned short* dst;
    if (id < 6144)       {             w = w1; MT = 16; KT = 2; Cin = 64;  dst = ws; }
    else if (id < 30720) { id -= 6144; w = w2; MT = 16; KT = 8; Cin = 256; dst = ws + A1_SZ/2; }
    else if (id < 43008) { id -= 30720; w = w3; MT = 8; KT = 8; Cin = 256; dst = ws + (A1_SZ+A2_SZ)/2; }
    else return;
    const int lane = id & 63;
    int f = id >> 6;
    const int kt = f % KT; f /= KT;
    const int mt = f % MT;
    const int tap = f / MT;
    const int h  = mt*16 + (lane & 15);               // A row (out-channel)
    const int c0 = kt*32 + (lane >> 4)*8;             // A k (in-channel), 8 consecutive
    unsigned short* o = dst + (size_t)id * 8;
    #pragma unroll
    for (int j = 0; j < 8; ++j)
        o[j] = f2bf(w[((size_t)(h*Cin + c0 + j))*3 + tap]);
}

__device__ __forceinline__ short8 ldA(const char* base, int frag, int lane) {
    return *(const short8*)(base + ((size_t)frag*64 + lane)*16);
}

// ---- one 64-wide t-tile through the full pipeline (inlined; straight-line) ----
__device__ __forceinline__ void process_tile(
    int t0, int b, char* lds,
    const float* __restrict__ x,
    const float* __restrict__ b_in, const float* __restrict__ b_mid,
    const float* __restrict__ b_out,
    const float* __restrict__ alpha, const float* __restrict__ beta,
    const char* wA1, const char* wA2, const char* wA3,
    float* __restrict__ out)
{
    unsigned short* xs = (unsigned short*)(lds + XS_OFF);   // [83 rows][72 ushort], row r <-> t0-19+r
    char* rs1 = lds + RS1_OFF;
    char* rs2 = lds + RS2_OFF;

    const int tid = threadIdx.x;
    const int lane = tid & 63;
    const int wid  = tid >> 6;
    const int l15 = lane & 15, l4 = lane >> 4;

    // ---------------- stage x -> xs bf16; zero rs1 halo rows 0,1 ----------------
    {
        const int rr = tid & 63, cg = tid >> 6;
        #pragma unroll
        for (int p = 0; p < 4; ++p) {
            const int c = cg*8 + p*2;
            const float* xc0 = x + ((size_t)b*C_ + c)*T_;
            const float* xc1 = xc0 + T_;
            {
                const int t = t0 - 19 + rr;
                float v0 = 0.f, v1 = 0.f;
                if (t >= 0) { v0 = xc0[t]; v1 = xc1[t]; }
                *(unsigned*)(&xs[rr*72 + c]) = cvtpk(v0, v1);
            }
            {
                const int r = rr + 64;
                if (r < 83) {
                    const int t = t0 - 19 + r;   // always in [45, 8191]
                    *(unsigned*)(&xs[r*72 + c]) = cvtpk(xc0[t], xc1[t]);
                }
            }
        }
        if (tid < 264) ((unsigned*)rs1)[tid] = 0u;   // rows 0,1 (t0-18,t0-17) = 0
    }
    __syncthreads();

    // ---- conv1: xs(64) -> rs1(256). Wave wid: mtiles {2wid,2wid+1} x all 5 ntiles.
    //      A1 x1 per tile. K=6 (3 taps x 2 ck) ----
    {
        const int mt0 = wid*2;
        f32x4 acc[2][5];
        #pragma unroll
        for (int m = 0; m < 2; ++m) {
            const f32x4 bv = *(const f32x4*)(b_in + (mt0+m)*16 + l4*4);
            #pragma unroll
            for (int nt = 0; nt < 5; ++nt) acc[m][nt] = bv;
        }
        int nb[5];
        #pragma unroll
        for (int nt = 0; nt < 5; ++nt)
            nb[nt] = XS_OFF + (16*nt + l15)*XS_ROWB + l4*16;
        short8 Ab[2][2];
        #pragma unroll
        for (int m = 0; m < 2; ++m) Ab[0][m] = ldA(wA1, (mt0+m)*2, lane);
        #pragma unroll
        for (int kt = 0; kt < 6; ++kt) {
            const int cur = kt & 1;
            const int tap = kt >> 1, ck = kt & 1;
            if (kt < 5) {
                const int kn = kt+1, tapn = kn>>1, ckn = kn&1;
                #pragma unroll
                for (int m = 0; m < 2; ++m)
                    Ab[cur^1][m] = ldA(wA1, (tapn*16 + mt0+m)*2 + ckn, lane);
            }
            __builtin_amdgcn_s_setprio(1);
            #pragma unroll
            for (int nt = 0; nt < 5; ++nt) {
                const short8 Bf = *(const short8*)(lds + nb[nt] + tap*XS_ROWB + ck*64);
                #pragma unroll
                for (int m = 0; m < 2; ++m)
                    acc[m][nt] = __builtin_amdgcn_mfma_f32_16x16x32_bf16(Ab[cur][m], Bf, acc[m][nt], 0, 0, 0);
            }
            __builtin_amdgcn_s_setprio(0);
        }
        #pragma unroll
        for (int nt = 0; nt < 5; ++nt) {
            const int tt16 = 16*nt + l15;
            const int t = t0 - 16 + tt16;
            char* dst0 = rs1 + (2 + tt16)*RS_ROWB;
            #pragma unroll
            for (int m = 0; m < 2; ++m) {
                const f32x4 a = acc[m][nt];
                unsigned long long pk = 0ull;
                if (t >= 0)
                    pk = (unsigned long long)cvtpk(a.x, a.y)
                       | ((unsigned long long)cvtpk(a.z, a.w) << 32);
                *(unsigned long long*)(dst0 + ((mt0+m)*16 + l4*4)*2) = pk;
            }
        }
    }
    __syncthreads();

    // ---- conv2: rs1(256) -> rs2(256). Wm=4/Wn=2 (balanced). K=24 ----
    {
        const int mg = wid >> 1, ng = wid & 1;
        const int ntb = ng ? 3 : 0, ncnt = ng ? 2 : 3;
        f32x4 acc[4][3];
        #pragma unroll
        for (int m = 0; m < 4; ++m) {
            const f32x4 bv = *(const f32x4*)(b_mid + (mg*4+m)*16 + l4*4);
            #pragma unroll
            for (int nt = 0; nt < 3; ++nt) acc[m][nt] = bv;
        }
        int nb[3];
        #pragma unroll
        for (int nt = 0; nt < 3; ++nt)
            nb[nt] = RS1_OFF + (16*(ntb+nt) + l15)*RS_ROWB + l4*16;
        short8 Ab[2][4];
        #pragma unroll
        for (int m = 0; m < 4; ++m) Ab[0][m] = ldA(wA2, (mg*4+m)*8, lane);
        #pragma unroll
        for (int kt = 0; kt < 24; ++kt) {
            const int cur = kt & 1;
            const int tap = kt >> 3, ck = kt & 7;
            if (kt < 23) {
                const int kn = kt+1, tapn = kn>>3, ckn = kn&7;
                #pragma unroll
                for (int m = 0; m < 4; ++m)
                    Ab[cur^1][m] = ldA(wA2, (tapn*16 + mg*4+m)*8 + ckn, lane);
            }
            __builtin_amdgcn_s_setprio(1);
            #pragma unroll
            for (int nt = 0; nt < 3; ++nt) if (nt < ncnt) {
                const short8 Bf = *(const short8*)(lds + nb[nt] + tap*RS_ROWB + ck*64);
                #pragma unroll
                for (int m = 0; m < 4; ++m)
                    acc[m][nt] = __builtin_amdgcn_mfma_f32_16x16x32_bf16(Ab[cur][m], Bf, acc[m][nt], 0, 0, 0);
            }
            __builtin_amdgcn_s_setprio(0);
        }
        #pragma unroll
        for (int nt = 0; nt < 3; ++nt) if (nt < ncnt) {
            const int tt16 = 16*(ntb+nt) + l15;
            const int r2row = tt16 - 14;             // rs2 row <-> t0-2+row
            if (r2row >= 0) {
                const int t = t0 - 16 + tt16;
                char* dst0 = rs2 + r2row*RS_ROWB;
                #pragma unroll
                for (int m = 0; m < 4; ++m) {
                    const f32x4 a = acc[m][nt];
                    unsigned long long pk = 0ull;
                    if (t >= 0)
                        pk = (unsigned long long)cvtpk(a.x, a.y)
                           | ((unsigned long long)cvtpk(a.z, a.w) << 32);
                    *(unsigned long long*)(dst0 + ((mg*4+m)*16 + l4*4)*2) = pk;
                }
            }
        }
    }
    __syncthreads();

    // ---- prefetch epilogue x into regs (global, no LDS dep; hides under conv3) ----
    float xv[8];
    {
        #pragma unroll
        for (int m = 0; m < 8; ++m) {
            const int e = tid + m*512;               // 4096 = 64c * 64t
            const int c = e >> 6, tl = e & 63;
            xv[m] = x[((size_t)b*C_ + c)*T_ + t0 + tl];
        }
    }

    // ---- conv3: rs2(256) -> rs3(128, fp32). Wave wid owns mtile wid x ALL 4 ntiles.
    //      A3 x1 per tile. 2-deep A prefetch ----
    {
        const int mt = wid;                          // 0..7 (M=128)
        f32x4 acc[4];
        {
            const f32x4 bv = *(const f32x4*)(b_out + mt*16 + l4*4);
            #pragma unroll
            for (int nt = 0; nt < 4; ++nt) acc[nt] = bv;
        }
        int nb[4];
        #pragma unroll
        for (int nt = 0; nt < 4; ++nt)
            nb[nt] = RS2_OFF + (16*nt + l15)*RS_ROWB + l4*16;
        short8 Ab[2];
        Ab[0] = ldA(wA3, mt*8 + 0, lane);            // kt=0: tap0,ck0
        Ab[1] = ldA(wA3, mt*8 + 1, lane);            // kt=1: tap0,ck1
        #pragma unroll
        for (int kt = 0; kt < 24; ++kt) {
            const int cur = kt & 1;
            const int tap = kt >> 3, ck = kt & 7;
            __builtin_amdgcn_s_setprio(1);
            #pragma unroll
            for (int nt = 0; nt < 4; ++nt) {
                const short8 Bf = *(const short8*)(lds + nb[nt] + tap*RS_ROWB + ck*64);
                acc[nt] = __builtin_amdgcn_mfma_f32_16x16x32_bf16(Ab[cur], Bf, acc[nt], 0, 0, 0);
            }
            __builtin_amdgcn_s_setprio(0);
            if (kt + 2 < 24) {
                const int kn = kt+2, tapn = kn>>3, ckn = kn&7;
                Ab[cur] = ldA(wA3, (tapn*8 + mt)*8 + ckn, lane);
            }
        }
        #pragma unroll
        for (int nt = 0; nt < 4; ++nt) {
            char* dst0 = lds + RS3_OFF + (16*nt + l15)*RS_ROWB;   // fp32 rows [64][132f]
            *(f32x4*)(dst0 + (mt*16 + l4*4)*4) = acc[nt];
        }
    }
    __syncthreads();

    // ---- epilogue: z = exp(alpha*tanh(log_s)+beta)*x + t ----
    {
        const float* rs3f = (const float*)(lds + RS3_OFF);
        #pragma unroll
        for (int m = 0; m < 8; ++m) {
            const int e = tid + m*512;
            const int c = e >> 6, tl = e & 63;
            const float ls = rs3f[tl*132 + c];
            const float tv = rs3f[tl*132 + c + 64];
            // tanh(ls) = 1 - 2/(exp(2*ls)+1)
            const float e2 = __expf(2.f * ls);
            const float th = fmaf(-2.f, __builtin_amdgcn_rcpf(e2 + 1.f), 1.f);
            const float lsv = fmaf(alpha[c], th, beta[c]);
            out[((size_t)b*C_ + c)*T_ + t0 + tl] = fmaf(__expf(lsv), xv[m], tv);
        }
    }
}

__global__ __launch_bounds__(512, 4)
void arflow_mfma(const float* __restrict__ x,
                 const float* __restrict__ b_in, const float* __restrict__ b_mid,
                 const float* __restrict__ b_out,
                 const float* __restrict__ alpha, const float* __restrict__ beta,
                 const char* __restrict__ wpk,
                 float* __restrict__ out)
{
    __shared__ __align__(16) char lds[LDS_BYTES];

    const char* wA1 = wpk;
    const char* wA2 = wpk + A1_SZ;
    const char* wA3 = wpk + A1_SZ + A2_SZ;

    const int b   = blockIdx.y;
    const int t00 = blockIdx.x * (TT * NSUB);

    process_tile(t00, b, lds, x, b_in, b_mid, b_out, alpha, beta, wA1, wA2, wA3, out);
    __syncthreads();   // WAR: tile 2 re-zeroes rs1 rows 0,1 / rewrites xs over rs3/epilogue reads
    process_tile(t00 + TT, b, lds, x, b_in, b_mid, b_out, alpha, beta, wA1, wA2, wA3, out);
}

extern "C" void kernel_launch(void* const* d_in, const int* in_sizes, int n_in,
                              void* d_out, int out_size, void* d_ws, size_t ws_size,
                              hipStream_t stream) {
    const float* x     = (const float*)d_in[0];
    const float* w_in  = (const float*)d_in[1];
    const float* b_in  = (const float*)d_in[2];
    const float* w_mid = (const float*)d_in[3];
    const float* b_mid = (const float*)d_in[4];
    const float* w_out = (const float*)d_in[5];
    const float* b_out = (const float*)d_in[6];
    const float* alpha = (const float*)d_in[7];
    const float* beta  = (const float*)d_in[8];
    float* out = (float*)d_out;

    if (ws_size < (size_t)AW_TOTAL) return;

    hipLaunchKernelGGL(pack_w, dim3(168), dim3(256), 0, stream,
                       w_in, w_mid, w_out, (unsigned short*)d_ws);
    hipLaunchKernelGGL(arflow_mfma, dim3(T_/(TT*NSUB), B_), dim3(512), 0, stream,
                       x, b_in, b_mid, b_out, alpha, beta, (const char*)d_ws, out);
}

// Round 9
// 327.007 us; speedup vs baseline: 3.1509x; 2.1505x over previous
//
#include <hip/hip_runtime.h>
#include <cmath>

typedef __attribute__((ext_vector_type(8))) short short8;
typedef __attribute__((ext_vector_type(4))) float f32x4;

#define B_   32
#define C_   64
#define T_   8192
#define H_   256
#define TT   64
#define NSUB 4               // t-tiles per block; per-iter pointer laundering stops CSE/LICM spill

// LDS geometry (bytes). Row r of rs1 <-> time t0-18+r; row r of rs2 <-> t0-2+r.
#define XS_ROWB 144          // 64ch*2B + 16B pad
#define RS_ROWB 528          // 256ch*2B + 16B pad (132 floats)
#define RS1_OFF 0            // 82 rows * 528 = 43296
#define RS2_OFF 43296        // 66 rows * 528 = 34848
#define XS_OFF  43296        // xs [83 rows][144B] aliases rs2 (disjoint lifetimes)
#define RS3_OFF 0            // rs3 fp32 [64 rows][528B] aliases rs1 (dead after conv2)
#define LDS_BYTES 78144      // 2 blocks/CU

// packed-A workspace (bytes): frag = ((tap*MT + mt)*KT + ck) * 1024
#define A1_SZ 98304          // 3*16*2 frags
#define A2_SZ 393216         // 3*16*8
#define A3_SZ 196608         // 3*8*8
#define AW_TOTAL (A1_SZ + A2_SZ + A3_SZ)

__device__ __forceinline__ unsigned short f2bf(float f) {
    unsigned u = __builtin_bit_cast(unsigned, f);
    u += 0x7fffu + ((u >> 16) & 1u);          // RNE
    return (unsigned short)(u >> 16);
}

// HW packed f32->bf16 (RNE): low16 = bf16(lo), high16 = bf16(hi)
__device__ __forceinline__ unsigned cvtpk(float lo, float hi) {
    unsigned r;
    asm("v_cvt_pk_bf16_f32 %0, %1, %2" : "=v"(r) : "v"(lo), "v"(hi));
    return r;
}

// ---- pack fp32 weights -> bf16 MFMA A-fragments in d_ws ----
__global__ void pack_w(const float* __restrict__ w1, const float* __restrict__ w2,
                       const float* __restrict__ w3, unsigned short* __restrict__ ws)
{
    int id = blockIdx.x * 256 + threadIdx.x;          // frag-lane id, 43008 total
    const float* w; int MT, KT, Cin; unsigned short* dst;
    if (id < 6144)       {             w = w1; MT = 16; KT = 2; Cin = 64;  dst = ws; }
    else if (id < 30720) { id -= 6144; w = w2; MT = 16; KT = 8; Cin = 256; dst = ws + A1_SZ/2; }
    else if (id < 43008) { id -= 30720; w = w3; MT = 8; KT = 8; Cin = 256; dst = ws + (A1_SZ+A2_SZ)/2; }
    else return;
    const int lane = id & 63;
    int f = id >> 6;
    const int kt = f % KT; f /= KT;
    const int mt = f % MT;
    const int tap = f / MT;
    const int h  = mt*16 + (lane & 15);               // A row (out-channel)
    const int c0 = kt*32 + (lane >> 4)*8;             // A k (in-channel), 8 consecutive
    unsigned short* o = dst + (size_t)id * 8;
    #pragma unroll
    for (int j = 0; j < 8; ++j)
        o[j] = f2bf(w[((size_t)(h*Cin + c0 + j))*3 + tap]);
}

__device__ __forceinline__ short8 ldA(const char* base, int frag, int lane) {
    return *(const short8*)(base + ((size_t)frag*64 + lane)*16);
}

// ---- one 64-wide t-tile through the full pipeline (inlined; straight-line) ----
__device__ __forceinline__ void process_tile(
    int t0, int b, char* lds,
    const float* __restrict__ x,
    const float* __restrict__ b_in, const float* __restrict__ b_mid,
    const float* __restrict__ b_out,
    const float* __restrict__ alpha, const float* __restrict__ beta,
    const char* wA1, const char* wA2, const char* wA3,
    float* __restrict__ out)
{
    unsigned short* xs = (unsigned short*)(lds + XS_OFF);   // [83 rows][72 ushort], row r <-> t0-19+r
    char* rs1 = lds + RS1_OFF;
    char* rs2 = lds + RS2_OFF;

    const int tid = threadIdx.x;
    const int lane = tid & 63;
    const int wid  = tid >> 6;
    const int l15 = lane & 15, l4 = lane >> 4;

    // ---------------- stage x -> xs bf16; zero rs1 halo rows 0,1 ----------------
    {
        const int rr = tid & 63, cg = tid >> 6;
        #pragma unroll
        for (int p = 0; p < 4; ++p) {
            const int c = cg*8 + p*2;
            const float* xc0 = x + ((size_t)b*C_ + c)*T_;
            const float* xc1 = xc0 + T_;
            {
                const int t = t0 - 19 + rr;
                float v0 = 0.f, v1 = 0.f;
                if (t >= 0) { v0 = xc0[t]; v1 = xc1[t]; }
                *(unsigned*)(&xs[rr*72 + c]) = cvtpk(v0, v1);
            }
            {
                const int r = rr + 64;
                if (r < 83) {
                    const int t = t0 - 19 + r;   // always in [45, 8191]
                    *(unsigned*)(&xs[r*72 + c]) = cvtpk(xc0[t], xc1[t]);
                }
            }
        }
        if (tid < 264) ((unsigned*)rs1)[tid] = 0u;   // rows 0,1 (t0-18,t0-17) = 0
    }
    __syncthreads();

    // ---- conv1: xs(64) -> rs1(256). Wave wid: mtiles {2wid,2wid+1} x all 5 ntiles.
    //      A1 x1 per tile. K=6 (3 taps x 2 ck) ----
    {
        const int mt0 = wid*2;
        f32x4 acc[2][5];
        #pragma unroll
        for (int m = 0; m < 2; ++m) {
            const f32x4 bv = *(const f32x4*)(b_in + (mt0+m)*16 + l4*4);
            #pragma unroll
            for (int nt = 0; nt < 5; ++nt) acc[m][nt] = bv;
        }
        int nb[5];
        #pragma unroll
        for (int nt = 0; nt < 5; ++nt)
            nb[nt] = XS_OFF + (16*nt + l15)*XS_ROWB + l4*16;
        short8 Ab[2][2];
        #pragma unroll
        for (int m = 0; m < 2; ++m) Ab[0][m] = ldA(wA1, (mt0+m)*2, lane);
        #pragma unroll
        for (int kt = 0; kt < 6; ++kt) {
            const int cur = kt & 1;
            const int tap = kt >> 1, ck = kt & 1;
            if (kt < 5) {
                const int kn = kt+1, tapn = kn>>1, ckn = kn&1;
                #pragma unroll
                for (int m = 0; m < 2; ++m)
                    Ab[cur^1][m] = ldA(wA1, (tapn*16 + mt0+m)*2 + ckn, lane);
            }
            __builtin_amdgcn_s_setprio(1);
            #pragma unroll
            for (int nt = 0; nt < 5; ++nt) {
                const short8 Bf = *(const short8*)(lds + nb[nt] + tap*XS_ROWB + ck*64);
                #pragma unroll
                for (int m = 0; m < 2; ++m)
                    acc[m][nt] = __builtin_amdgcn_mfma_f32_16x16x32_bf16(Ab[cur][m], Bf, acc[m][nt], 0, 0, 0);
            }
            __builtin_amdgcn_s_setprio(0);
        }
        #pragma unroll
        for (int nt = 0; nt < 5; ++nt) {
            const int tt16 = 16*nt + l15;
            const int t = t0 - 16 + tt16;
            char* dst0 = rs1 + (2 + tt16)*RS_ROWB;
            #pragma unroll
            for (int m = 0; m < 2; ++m) {
                const f32x4 a = acc[m][nt];
                unsigned long long pk = 0ull;
                if (t >= 0)
                    pk = (unsigned long long)cvtpk(a.x, a.y)
                       | ((unsigned long long)cvtpk(a.z, a.w) << 32);
                *(unsigned long long*)(dst0 + ((mt0+m)*16 + l4*4)*2) = pk;
            }
        }
    }
    __syncthreads();

    // ---- conv2: rs1(256) -> rs2(256). Wm=4/Wn=2 (balanced). K=24 ----
    {
        const int mg = wid >> 1, ng = wid & 1;
        const int ntb = ng ? 3 : 0, ncnt = ng ? 2 : 3;
        f32x4 acc[4][3];
        #pragma unroll
        for (int m = 0; m < 4; ++m) {
            const f32x4 bv = *(const f32x4*)(b_mid + (mg*4+m)*16 + l4*4);
            #pragma unroll
            for (int nt = 0; nt < 3; ++nt) acc[m][nt] = bv;
        }
        int nb[3];
        #pragma unroll
        for (int nt = 0; nt < 3; ++nt)
            nb[nt] = RS1_OFF + (16*(ntb+nt) + l15)*RS_ROWB + l4*16;
        short8 Ab[2][4];
        #pragma unroll
        for (int m = 0; m < 4; ++m) Ab[0][m] = ldA(wA2, (mg*4+m)*8, lane);
        #pragma unroll
        for (int kt = 0; kt < 24; ++kt) {
            const int cur = kt & 1;
            const int tap = kt >> 3, ck = kt & 7;
            if (kt < 23) {
                const int kn = kt+1, tapn = kn>>3, ckn = kn&7;
                #pragma unroll
                for (int m = 0; m < 4; ++m)
                    Ab[cur^1][m] = ldA(wA2, (tapn*16 + mg*4+m)*8 + ckn, lane);
            }
            __builtin_amdgcn_s_setprio(1);
            #pragma unroll
            for (int nt = 0; nt < 3; ++nt) if (nt < ncnt) {
                const short8 Bf = *(const short8*)(lds + nb[nt] + tap*RS_ROWB + ck*64);
                #pragma unroll
                for (int m = 0; m < 4; ++m)
                    acc[m][nt] = __builtin_amdgcn_mfma_f32_16x16x32_bf16(Ab[cur][m], Bf, acc[m][nt], 0, 0, 0);
            }
            __builtin_amdgcn_s_setprio(0);
        }
        #pragma unroll
        for (int nt = 0; nt < 3; ++nt) if (nt < ncnt) {
            const int tt16 = 16*(ntb+nt) + l15;
            const int r2row = tt16 - 14;             // rs2 row <-> t0-2+row
            if (r2row >= 0) {
                const int t = t0 - 16 + tt16;
                char* dst0 = rs2 + r2row*RS_ROWB;
                #pragma unroll
                for (int m = 0; m < 4; ++m) {
                    const f32x4 a = acc[m][nt];
                    unsigned long long pk = 0ull;
                    if (t >= 0)
                        pk = (unsigned long long)cvtpk(a.x, a.y)
                           | ((unsigned long long)cvtpk(a.z, a.w) << 32);
                    *(unsigned long long*)(dst0 + ((mg*4+m)*16 + l4*4)*2) = pk;
                }
            }
        }
    }
    __syncthreads();

    // ---- prefetch epilogue x into regs (global, no LDS dep; hides under conv3) ----
    float xv[8];
    {
        #pragma unroll
        for (int m = 0; m < 8; ++m) {
            const int e = tid + m*512;               // 4096 = 64c * 64t
            const int c = e >> 6, tl = e & 63;
            xv[m] = x[((size_t)b*C_ + c)*T_ + t0 + tl];
        }
    }

    // ---- conv3: rs2(256) -> rs3(128, fp32). Wave wid owns mtile wid x ALL 4 ntiles.
    //      A3 x1 per tile. 2-deep A prefetch ----
    {
        const int mt = wid;                          // 0..7 (M=128)
        f32x4 acc[4];
        {
            const f32x4 bv = *(const f32x4*)(b_out + mt*16 + l4*4);
            #pragma unroll
            for (int nt = 0; nt < 4; ++nt) acc[nt] = bv;
        }
        int nb[4];
        #pragma unroll
        for (int nt = 0; nt < 4; ++nt)
            nb[nt] = RS2_OFF + (16*nt + l15)*RS_ROWB + l4*16;
        short8 Ab[2];
        Ab[0] = ldA(wA3, mt*8 + 0, lane);            // kt=0: tap0,ck0
        Ab[1] = ldA(wA3, mt*8 + 1, lane);            // kt=1: tap0,ck1
        #pragma unroll
        for (int kt = 0; kt < 24; ++kt) {
            const int cur = kt & 1;
            const int tap = kt >> 3, ck = kt & 7;
            __builtin_amdgcn_s_setprio(1);
            #pragma unroll
            for (int nt = 0; nt < 4; ++nt) {
                const short8 Bf = *(const short8*)(lds + nb[nt] + tap*RS_ROWB + ck*64);
                acc[nt] = __builtin_amdgcn_mfma_f32_16x16x32_bf16(Ab[cur], Bf, acc[nt], 0, 0, 0);
            }
            __builtin_amdgcn_s_setprio(0);
            if (kt + 2 < 24) {
                const int kn = kt+2, tapn = kn>>3, ckn = kn&7;
                Ab[cur] = ldA(wA3, (tapn*8 + mt)*8 + ckn, lane);
            }
        }
        #pragma unroll
        for (int nt = 0; nt < 4; ++nt) {
            char* dst0 = lds + RS3_OFF + (16*nt + l15)*RS_ROWB;   // fp32 rows [64][132f]
            *(f32x4*)(dst0 + (mt*16 + l4*4)*4) = acc[nt];
        }
    }
    __syncthreads();

    // ---- epilogue: z = exp(alpha*tanh(log_s)+beta)*x + t ----
    {
        const float* rs3f = (const float*)(lds + RS3_OFF);
        #pragma unroll
        for (int m = 0; m < 8; ++m) {
            const int e = tid + m*512;
            const int c = e >> 6, tl = e & 63;
            const float ls = rs3f[tl*132 + c];
            const float tv = rs3f[tl*132 + c + 64];
            // tanh(ls) = 1 - 2/(exp(2*ls)+1)
            const float e2 = __expf(2.f * ls);
            const float th = fmaf(-2.f, __builtin_amdgcn_rcpf(e2 + 1.f), 1.f);
            const float lsv = fmaf(alpha[c], th, beta[c]);
            out[((size_t)b*C_ + c)*T_ + t0 + tl] = fmaf(__expf(lsv), xv[m], tv);
        }
    }
}

__global__ __launch_bounds__(512, 4)
void arflow_mfma(const float* __restrict__ x,
                 const float* __restrict__ b_in, const float* __restrict__ b_mid,
                 const float* __restrict__ b_out,
                 const float* __restrict__ alpha, const float* __restrict__ beta,
                 const char* __restrict__ wpk,
                 float* __restrict__ out)
{
    __shared__ __align__(16) char lds[LDS_BYTES];

    const int b   = blockIdx.y;
    const int t00 = blockIdx.x * (TT * NSUB);

    #pragma unroll 1
    for (int s = 0; s < NSUB; ++s) {
        // Kill cross-iteration load CSE / LICM of weight-fragment loads (spill cause
        // in R7/R8): launder uniform pointers through opaque SGPR asm + full compiler
        // memory barrier. Zero runtime cost; forces each tile to reload its A frags.
        const char*  wA1 = wpk;
        const char*  wA2 = wpk + A1_SZ;
        const char*  wA3 = wpk + A1_SZ + A2_SZ;
        const float* xp  = x;
        float*       op  = out;
        asm volatile("" : "+s"(wA1), "+s"(wA2), "+s"(wA3), "+s"(xp), "+s"(op) :: "memory");

        process_tile(t00 + s*TT, b, lds, xp, b_in, b_mid, b_out, alpha, beta,
                     wA1, wA2, wA3, op);
        __syncthreads();   // WAR: next iter re-zeroes rs1 rows 0,1 / rewrites xs over rs3 reads
    }
}

extern "C" void kernel_launch(void* const* d_in, const int* in_sizes, int n_in,
                              void* d_out, int out_size, void* d_ws, size_t ws_size,
                              hipStream_t stream) {
    const float* x     = (const float*)d_in[0];
    const float* w_in  = (const float*)d_in[1];
    const float* b_in  = (const float*)d_in[2];
    const float* w_mid = (const float*)d_in[3];
    const float* b_mid = (const float*)d_in[4];
    const float* w_out = (const float*)d_in[5];
    const float* b_out = (const float*)d_in[6];
    const float* alpha = (const float*)d_in[7];
    const float* beta  = (const float*)d_in[8];
    float* out = (float*)d_out;

    if (ws_size < (size_t)AW_TOTAL) return;

    hipLaunchKernelGGL(pack_w, dim3(168), dim3(256), 0, stream,
                       w_in, w_mid, w_out, (unsigned short*)d_ws);
    hipLaunchKernelGGL(arflow_mfma, dim3(T_/(TT*NSUB), B_), dim3(512), 0, stream,
                       x, b_in, b_mid, b_out, alpha, beta, (const char*)d_ws, out);
}

// Round 10
// 234.063 us; speedup vs baseline: 4.4021x; 1.3971x over previous
//
#include <hip/hip_runtime.h>
#include <cmath>

typedef __attribute__((ext_vector_type(8)))  short short8;
typedef __attribute__((ext_vector_type(4)))  float f32x4;
typedef __attribute__((ext_vector_type(16))) float f32x16;

#define B_   32
#define C_   64
#define T_   8192
#define H_   256
#define TT   128

// LDS: ONE in-place buffer (rs1 -> rs2 -> rs3, barrier-separated) + xs.
//   buf row r as rs1 <-> t0-18+r (rows 0..145; conv2 reads rows 14..145)
//   buf row r as rs2 <-> t0-2+r  (rows 0..129, stored after conv2 read-barrier)
//   buf row r as rs3 <-> t0+r    (rows 0..127 fp32, stored after conv3 read-barrier)
//   xs  row r        <-> t0-19+r (rows 0..146 staged; 147..161 garbage pad for masked reads)
#define RS_ROWB 528          // 256ch*2B + 16pad; 528/16=33 -> b128 @row-stride conflict-free
#define XS_ROWB 144          // 64ch*2B + 16pad
#define BUF_OFF 0            // 146 rows * 528 = 77088
#define XS_OFF  77088
#define LDS_BYTES (77088 + 162*144)   // 100416 -> 1 block/CU, 2 waves/EU (256-reg budget)

// packed-A (32x32x16 frags): frag id = (tap*MT + mt)*KT + kt ; 1KB each
#define A1_SZ  98304         // 3*8*4
#define A2_SZ  393216        // 3*8*16
#define A3_SZ  196608        // 3*4*16
#define AW_TOTAL (A1_SZ + A2_SZ + A3_SZ)

__device__ __forceinline__ unsigned short f2bf(float f) {
    unsigned u = __builtin_bit_cast(unsigned, f);
    u += 0x7fffu + ((u >> 16) & 1u);
    return (unsigned short)(u >> 16);
}
__device__ __forceinline__ unsigned cvtpk(float lo, float hi) {
    unsigned r;
    asm("v_cvt_pk_bf16_f32 %0, %1, %2" : "=v"(r) : "v"(lo), "v"(hi));
    return r;
}

// ---- pack fp32 weights -> bf16 32x32x16 A-fragments ----
// A-frag layout: lane l holds A[row = mt*32 + (l&31)][k = kt*16 + (l>>5)*8 + j], j=0..7
__global__ void pack_w(const float* __restrict__ w1, const float* __restrict__ w2,
                       const float* __restrict__ w3, unsigned short* __restrict__ ws)
{
    int id = blockIdx.x * 256 + threadIdx.x;          // 43008 frag-lane ids
    const float* w; int MT, KT, Cin; unsigned short* dst;
    if (id < 6144)       {             w = w1; MT = 8; KT = 4;  Cin = 64;  dst = ws; }
    else if (id < 30720) { id -= 6144; w = w2; MT = 8; KT = 16; Cin = 256; dst = ws + A1_SZ/2; }
    else if (id < 43008) { id -= 30720; w = w3; MT = 4; KT = 16; Cin = 256; dst = ws + (A1_SZ+A2_SZ)/2; }
    else return;
    const int lane = id & 63;
    int f = id >> 6;
    const int kt = f % KT; f /= KT;
    const int mt = f % MT;
    const int tap = f / MT;
    const int h  = mt*32 + (lane & 31);
    const int c0 = kt*16 + (lane >> 5)*8;
    unsigned short* o = dst + (size_t)id * 8;
    #pragma unroll
    for (int j = 0; j < 8; ++j)
        o[j] = f2bf(w[((size_t)(h*Cin + c0 + j))*3 + tap]);
}

__device__ __forceinline__ short8 ldA(const char* base, int frag, int lane) {
    return *(const short8*)(base + ((size_t)frag*64 + lane)*16);
}

__global__ __launch_bounds__(512, 2)
void arflow_mfma(const float* __restrict__ x,
                 const float* __restrict__ b_in, const float* __restrict__ b_mid,
                 const float* __restrict__ b_out,
                 const float* __restrict__ alpha, const float* __restrict__ beta,
                 const char* __restrict__ wpk,
                 float* __restrict__ out)
{
    __shared__ __align__(16) char lds[LDS_BYTES];
    unsigned short* xs = (unsigned short*)(lds + XS_OFF);
    char* buf = lds + BUF_OFF;

    const char* wA1 = wpk;
    const char* wA2 = wpk + A1_SZ;
    const char* wA3 = wpk + A1_SZ + A2_SZ;

    const int b   = blockIdx.y;
    const int t0  = blockIdx.x * TT;
    const int tid = threadIdx.x;
    const int lane = tid & 63;
    const int wid  = tid >> 6;
    const int l31 = lane & 31, l5 = lane >> 5;

    // ---------------- stage x -> xs bf16 (147 rows; t0+127 <= 8191 always) ----------------
    {
        const int rr = tid & 127, cg = tid >> 7;
        const int t = t0 - 19 + rr;
        #pragma unroll
        for (int p = 0; p < 8; ++p) {
            const int c = cg*16 + p*2;
            const float* xc0 = x + ((size_t)b*C_ + c)*T_;
            const float* xc1 = xc0 + T_;
            float v0 = 0.f, v1 = 0.f;
            if (t >= 0) { v0 = xc0[t]; v1 = xc1[t]; }
            *(unsigned*)(&xs[rr*72 + c]) = cvtpk(v0, v1);
            if (rr < 19) {
                const int t2 = t + 128;              // >= 109, always valid
                *(unsigned*)(&xs[(rr+128)*72 + c]) = cvtpk(xc0[t2], xc1[t2]);
            }
        }
    }
    __syncthreads();

    // ---- conv1: xs(64) -> rs1(256) in buf. Wave wid owns mt32=wid, ALL 5 nt32 (A1 x1).
    //      K = 12 kt16 (tap = kt>>2, ck = kt&3). N-tile n at t = t0-16+32n+col ----
    {
        const int mt = wid;
        f32x4 bq[4];
        #pragma unroll
        for (int q = 0; q < 4; ++q)
            bq[q] = *(const f32x4*)(b_in + mt*32 + q*8 + l5*4);
        f32x16 acc[5];
        #pragma unroll
        for (int nt = 0; nt < 5; ++nt)
            #pragma unroll
            for (int q = 0; q < 4; ++q) {
                acc[nt][4*q+0] = bq[q][0]; acc[nt][4*q+1] = bq[q][1];
                acc[nt][4*q+2] = bq[q][2]; acc[nt][4*q+3] = bq[q][3];
            }
        int nb[5];
        #pragma unroll
        for (int nt = 0; nt < 5; ++nt)
            nb[nt] = XS_OFF + (32*nt + l31)*XS_ROWB + l5*16;
        short8 Ab[2];
        Ab[0] = ldA(wA1, mt*4, lane);                 // tap0,ck0
        #pragma unroll
        for (int kt = 0; kt < 12; ++kt) {
            const int cur = kt & 1;
            const int tap = kt >> 2, ck = kt & 3;
            if (kt < 11) {
                const int kn = kt + 1;
                Ab[cur^1] = ldA(wA1, ((kn>>2)*8 + mt)*4 + (kn&3), lane);
            }
            __builtin_amdgcn_s_setprio(1);
            #pragma unroll
            for (int nt = 0; nt < 5; ++nt) {
                const short8 Bf = *(const short8*)(lds + nb[nt] + tap*XS_ROWB + ck*32);
                acc[nt] = __builtin_amdgcn_mfma_f32_32x32x16_bf16(Ab[cur], Bf, acc[nt], 0, 0, 0);
            }
            __builtin_amdgcn_s_setprio(0);
        }
        // store bf16; C layout: col=l31 (time), ch = mt*32 + 8q + 4*l5 + (reg&3)
        #pragma unroll
        for (int nt = 0; nt < 5; ++nt) {
            const int rb = 2 + 32*nt + l31;          // buf row (rs1 <-> t0-18+rb)
            const int t  = t0 - 16 + 32*nt + l31;
            if (rb <= 145) {
                char* dst0 = buf + rb*RS_ROWB + mt*64;
                #pragma unroll
                for (int q = 0; q < 4; ++q) {
                    unsigned long long pk = 0ull;
                    if (t >= 0)
                        pk = (unsigned long long)cvtpk(acc[nt][4*q+0], acc[nt][4*q+1])
                           | ((unsigned long long)cvtpk(acc[nt][4*q+2], acc[nt][4*q+3]) << 32);
                    *(unsigned long long*)(dst0 + q*16 + l5*8) = pk;
                }
            }
        }
    }
    __syncthreads();

    // ---- conv2: rs1 -> rs2 IN-PLACE. Wm=4/Wn=2: wave = (mg, ng), mts {2mg,2mg+1},
    //      nt set ng?{3,4}:{0,1,2}. K = 48 kt16. Output t = t0-2+32n+col ----
    {
        const int mg = wid >> 1, ng = wid & 1;
        const int mt0 = mg*2;
        const int ntb = ng ? 3 : 0, ncnt = ng ? 2 : 3;
        f32x16 acc[2][3];
        #pragma unroll
        for (int m = 0; m < 2; ++m) {
            f32x4 bq[4];
            #pragma unroll
            for (int q = 0; q < 4; ++q)
                bq[q] = *(const f32x4*)(b_mid + (mt0+m)*32 + q*8 + l5*4);
            #pragma unroll
            for (int nt = 0; nt < 3; ++nt)
                #pragma unroll
                for (int q = 0; q < 4; ++q) {
                    acc[m][nt][4*q+0] = bq[q][0]; acc[m][nt][4*q+1] = bq[q][1];
                    acc[m][nt][4*q+2] = bq[q][2]; acc[m][nt][4*q+3] = bq[q][3];
                }
        }
        int nb[3];
        #pragma unroll
        for (int nt = 0; nt < 3; ++nt)
            nb[nt] = BUF_OFF + (14 + 32*(ntb+nt) + l31)*RS_ROWB + l5*16;
        short8 Ab[2][2];
        #pragma unroll
        for (int m = 0; m < 2; ++m) Ab[0][m] = ldA(wA2, (mt0+m)*16, lane);
        #pragma unroll
        for (int kt = 0; kt < 48; ++kt) {
            const int cur = kt & 1;
            const int tap = kt >> 4, ck = kt & 15;
            if (kt < 47) {
                const int kn = kt + 1, tapn = kn >> 4, ckn = kn & 15;
                #pragma unroll
                for (int m = 0; m < 2; ++m)
                    Ab[cur^1][m] = ldA(wA2, (tapn*8 + mt0+m)*16 + ckn, lane);
            }
            __builtin_amdgcn_s_setprio(1);
            #pragma unroll
            for (int nt = 0; nt < 3; ++nt) if (nt < ncnt) {
                const short8 Bf = *(const short8*)(lds + nb[nt] + tap*RS_ROWB + ck*32);
                #pragma unroll
                for (int m = 0; m < 2; ++m)
                    acc[m][nt] = __builtin_amdgcn_mfma_f32_32x32x16_bf16(Ab[cur][m], Bf, acc[m][nt], 0, 0, 0);
            }
            __builtin_amdgcn_s_setprio(0);
        }
        __syncthreads();                 // ALL rs1 reads done before in-place overwrite
        #pragma unroll
        for (int nt = 0; nt < 3; ++nt) if (nt < ncnt) {
            const int r2 = 32*(ntb+nt) + l31;        // rs2 row <-> t0-2+r2
            const int t  = t0 - 2 + r2;
            if (r2 <= 129) {
                #pragma unroll
                for (int m = 0; m < 2; ++m) {
                    char* dst0 = buf + r2*RS_ROWB + (mt0+m)*64;
                    #pragma unroll
                    for (int q = 0; q < 4; ++q) {
                        unsigned long long pk = 0ull;
                        if (t >= 0)
                            pk = (unsigned long long)cvtpk(acc[m][nt][4*q+0], acc[m][nt][4*q+1])
                               | ((unsigned long long)cvtpk(acc[m][nt][4*q+2], acc[m][nt][4*q+3]) << 32);
                        *(unsigned long long*)(dst0 + q*16 + l5*8) = pk;
                    }
                }
            }
        }
    }

    // ---- prefetch epilogue x into regs (no LDS dep; hides under conv3) ----
    float xv[16];
    #pragma unroll
    for (int m = 0; m < 16; ++m) {
        const int e = tid + m*512;                   // 8192 = 64c * 128t
        const int c = e >> 7, tl = e & 127;
        xv[m] = x[((size_t)b*C_ + c)*T_ + t0 + tl];
    }
    __syncthreads();

    // ---- conv3: rs2 -> rs3(128, fp32) IN-PLACE. Wm=4/Wn=2: mt=wid&3, ng=wid>>2,
    //      nt {2ng, 2ng+1}. Output t = t0+32n+col. Depth-3 A ring ----
    {
        const int mt = wid & 3, ng = wid >> 2;
        const int ntb = ng*2;
        f32x4 bq[4];
        #pragma unroll
        for (int q = 0; q < 4; ++q)
            bq[q] = *(const f32x4*)(b_out + mt*32 + q*8 + l5*4);
        f32x16 acc[2];
        #pragma unroll
        for (int nt = 0; nt < 2; ++nt)
            #pragma unroll
            for (int q = 0; q < 4; ++q) {
                acc[nt][4*q+0] = bq[q][0]; acc[nt][4*q+1] = bq[q][1];
                acc[nt][4*q+2] = bq[q][2]; acc[nt][4*q+3] = bq[q][3];
            }
        int nb[2];
        #pragma unroll
        for (int nt = 0; nt < 2; ++nt)
            nb[nt] = BUF_OFF + (32*(ntb+nt) + l31)*RS_ROWB + l5*16;
        short8 Ab[4];
        Ab[0] = ldA(wA3, mt*16 + 0, lane);
        Ab[1] = ldA(wA3, mt*16 + 1, lane);
        Ab[2] = ldA(wA3, mt*16 + 2, lane);
        #pragma unroll
        for (int kt = 0; kt < 48; ++kt) {
            const int cur = kt & 3;
            const int tap = kt >> 4, ck = kt & 15;
            if (kt < 45) {
                const int kn = kt + 3;
                Ab[(kt+3)&3] = ldA(wA3, ((kn>>4)*4 + mt)*16 + (kn&15), lane);
            }
            __builtin_amdgcn_s_setprio(1);
            #pragma unroll
            for (int nt = 0; nt < 2; ++nt) {
                const short8 Bf = *(const short8*)(lds + nb[nt] + tap*RS_ROWB + ck*32);
                acc[nt] = __builtin_amdgcn_mfma_f32_32x32x16_bf16(Ab[cur], Bf, acc[nt], 0, 0, 0);
            }
            __builtin_amdgcn_s_setprio(0);
        }
        __syncthreads();                 // ALL rs2 reads done before fp32 overwrite
        #pragma unroll
        for (int nt = 0; nt < 2; ++nt) {
            const int row = 32*(ntb+nt) + l31;       // 0..127, rs3 <-> t0+row
            char* dst0 = buf + row*RS_ROWB + mt*128; // ch byte = ch*4
            #pragma unroll
            for (int q = 0; q < 4; ++q) {
                f32x4 v;
                v[0] = acc[nt][4*q+0]; v[1] = acc[nt][4*q+1];
                v[2] = acc[nt][4*q+2]; v[3] = acc[nt][4*q+3];
                *(f32x4*)(dst0 + q*32 + l5*16) = v;
            }
        }
    }
    __syncthreads();

    // ---- epilogue: z = exp(alpha*tanh(log_s)+beta)*x + t ----
    {
        const float* rs3f = (const float*)buf;       // [128 rows][132 floats]
        #pragma unroll
        for (int m = 0; m < 16; ++m) {
            const int e = tid + m*512;
            const int c = e >> 7, tl = e & 127;
            const float ls = rs3f[tl*132 + c];
            const float tv = rs3f[tl*132 + c + 64];
            const float e2 = __expf(2.f * ls);
            const float th = fmaf(-2.f, __builtin_amdgcn_rcpf(e2 + 1.f), 1.f);
            const float lsv = fmaf(alpha[c], th, beta[c]);
            out[((size_t)b*C_ + c)*T_ + t0 + tl] = fmaf(__expf(lsv), xv[m], tv);
        }
    }
}

extern "C" void kernel_launch(void* const* d_in, const int* in_sizes, int n_in,
                              void* d_out, int out_size, void* d_ws, size_t ws_size,
                              hipStream_t stream) {
    const float* x     = (const float*)d_in[0];
    const float* w_in  = (const float*)d_in[1];
    const float* b_in  = (const float*)d_in[2];
    const float* w_mid = (const float*)d_in[3];
    const float* b_mid = (const float*)d_in[4];
    const float* w_out = (const float*)d_in[5];
    const float* b_out = (const float*)d_in[6];
    const float* alpha = (const float*)d_in[7];
    const float* beta  = (const float*)d_in[8];
    float* out = (float*)d_out;

    if (ws_size < (size_t)AW_TOTAL) return;

    hipLaunchKernelGGL(pack_w, dim3(168), dim3(256), 0, stream,
                       w_in, w_mid, w_out, (unsigned short*)d_ws);
    hipLaunchKernelGGL(arflow_mfma, dim3(T_/TT, B_), dim3(512), 0, stream,
                       x, b_in, b_mid, b_out, alpha, beta, (const char*)d_ws, out);
}

// Round 11
// 215.967 us; speedup vs baseline: 4.7710x; 1.0838x over previous
//
#include <hip/hip_runtime.h>
#include <cmath>

typedef __attribute__((ext_vector_type(8)))  short short8;
typedef __attribute__((ext_vector_type(4)))  float f32x4;
typedef __attribute__((ext_vector_type(16))) float f32x16;

#define B_   32
#define C_   64
#define T_   8192
#define H_   256
#define TT   128

// LDS: ONE in-place buffer (rs1 -> rs2 -> rs3, barrier-separated) + xs.
//   buf row r as rs1 <-> t0-18+r (rows 0..145; conv2 reads rows 14..145)
//   buf row r as rs2 <-> t0-2+r  (rows 0..129, stored after conv2 read-barrier)
//   buf row r as rs3 <-> t0+r    (rows 0..127 fp32, stored after conv3 read-barrier)
//   xs  row r        <-> t0-19+r (rows 0..146 staged; rest garbage pad for masked reads)
#define RS_ROWB 528          // 256ch*2B + 16pad
#define XS_ROWB 144          // 64ch*2B + 16pad
#define BUF_OFF 0            // 146 rows * 528 = 77088
#define XS_OFF  77088
#define LDS_BYTES (77088 + 162*144)   // 100416 -> 1 block/CU, 2 waves/EU (256-reg budget)

// packed-A (32x32x16 frags): frag id = (tap*MT + mt)*KT + kt ; 1KB each
#define A1_SZ  98304         // 3*8*4
#define A2_SZ  393216        // 3*8*16
#define A3_SZ  196608        // 3*4*16
#define AW_TOTAL (A1_SZ + A2_SZ + A3_SZ)

__device__ __forceinline__ unsigned short f2bf(float f) {
    unsigned u = __builtin_bit_cast(unsigned, f);
    u += 0x7fffu + ((u >> 16) & 1u);
    return (unsigned short)(u >> 16);
}
__device__ __forceinline__ unsigned cvtpk(float lo, float hi) {
    unsigned r;
    asm("v_cvt_pk_bf16_f32 %0, %1, %2" : "=v"(r) : "v"(lo), "v"(hi));
    return r;
}

// ---- pack fp32 weights -> bf16 32x32x16 A-fragments ----
// lane l holds A[row = mt*32 + (l&31)][k = kt*16 + (l>>5)*8 + j], j=0..7
__global__ void pack_w(const float* __restrict__ w1, const float* __restrict__ w2,
                       const float* __restrict__ w3, unsigned short* __restrict__ ws)
{
    int id = blockIdx.x * 256 + threadIdx.x;          // 43008 frag-lane ids
    const float* w; int MT, KT, Cin; unsigned short* dst;
    if (id < 6144)       {             w = w1; MT = 8; KT = 4;  Cin = 64;  dst = ws; }
    else if (id < 30720) { id -= 6144; w = w2; MT = 8; KT = 16; Cin = 256; dst = ws + A1_SZ/2; }
    else if (id < 43008) { id -= 30720; w = w3; MT = 4; KT = 16; Cin = 256; dst = ws + (A1_SZ+A2_SZ)/2; }
    else return;
    const int lane = id & 63;
    int f = id >> 6;
    const int kt = f % KT; f /= KT;
    const int mt = f % MT;
    const int tap = f / MT;
    const int h  = mt*32 + (lane & 31);
    const int c0 = kt*16 + (lane >> 5)*8;
    unsigned short* o = dst + (size_t)id * 8;
    #pragma unroll
    for (int j = 0; j < 8; ++j)
        o[j] = f2bf(w[((size_t)(h*Cin + c0 + j))*3 + tap]);
}

__device__ __forceinline__ short8 ldA(const char* base, int frag, int lane) {
    return *(const short8*)(base + ((size_t)frag*64 + lane)*16);
}

__global__ __launch_bounds__(512, 2)
void arflow_mfma(const float* __restrict__ x,
                 const float* __restrict__ b_in, const float* __restrict__ b_mid,
                 const float* __restrict__ b_out,
                 const float* __restrict__ alpha, const float* __restrict__ beta,
                 const char* __restrict__ wpk,
                 float* __restrict__ out)
{
    __shared__ __align__(16) char lds[LDS_BYTES];
    unsigned short* xs = (unsigned short*)(lds + XS_OFF);
    char* buf = lds + BUF_OFF;

    const char* wA1 = wpk;
    const char* wA2 = wpk + A1_SZ;
    const char* wA3 = wpk + A1_SZ + A2_SZ;

    const int b   = blockIdx.y;
    const int t0  = blockIdx.x * TT;
    const int tid = threadIdx.x;
    const int lane = tid & 63;
    const int wid  = tid >> 6;
    const int l31 = lane & 31, l5 = lane >> 5;

    // ---------------- stage x -> xs bf16 (147 rows) ----------------
    {
        const int rr = tid & 127, cg = tid >> 7;
        const int t = t0 - 19 + rr;
        #pragma unroll
        for (int p = 0; p < 8; ++p) {
            const int c = cg*16 + p*2;
            const float* xc0 = x + ((size_t)b*C_ + c)*T_;
            const float* xc1 = xc0 + T_;
            float v0 = 0.f, v1 = 0.f;
            if (t >= 0) { v0 = xc0[t]; v1 = xc1[t]; }
            *(unsigned*)(&xs[rr*72 + c]) = cvtpk(v0, v1);
            if (rr < 19) {
                const int t2 = t + 128;              // >= 109, always valid
                *(unsigned*)(&xs[(rr+128)*72 + c]) = cvtpk(xc0[t2], xc1[t2]);
            }
        }
    }
    __syncthreads();

    // ---- conv1: xs(64) -> rs1(256). Wave wid owns mt=wid, ALL 5 nt (A1 x1).
    //      K = 12 kt16. A-ring depth 4, B-ring depth 2 ----
    {
        const int mt = wid;
        f32x4 bq[4];
        #pragma unroll
        for (int q = 0; q < 4; ++q)
            bq[q] = *(const f32x4*)(b_in + mt*32 + q*8 + l5*4);
        f32x16 acc[5];
        #pragma unroll
        for (int nt = 0; nt < 5; ++nt)
            #pragma unroll
            for (int q = 0; q < 4; ++q) {
                acc[nt][4*q+0] = bq[q][0]; acc[nt][4*q+1] = bq[q][1];
                acc[nt][4*q+2] = bq[q][2]; acc[nt][4*q+3] = bq[q][3];
            }
        int nb[5];
        #pragma unroll
        for (int nt = 0; nt < 5; ++nt)
            nb[nt] = XS_OFF + (32*nt + l31)*XS_ROWB + l5*16;

        short8 Ar[4];
        short8 Br[2][5];
        #pragma unroll
        for (int k = 0; k < 3; ++k)
            Ar[k] = ldA(wA1, ((k>>2)*8 + mt)*4 + (k&3), lane);
        #pragma unroll
        for (int nt = 0; nt < 5; ++nt)
            Br[0][nt] = *(const short8*)(lds + nb[nt]);            // kt=0: tap0,ck0
        #pragma unroll
        for (int kt = 0; kt < 12; ++kt) {
            if (kt + 3 < 12) {
                const int kn = kt + 3;
                Ar[(kt+3)&3] = ldA(wA1, ((kn>>2)*8 + mt)*4 + (kn&3), lane);
            }
            if (kt + 1 < 12) {
                const int kn = kt + 1, tapn = kn >> 2, ckn = kn & 3;
                #pragma unroll
                for (int nt = 0; nt < 5; ++nt)
                    Br[(kt+1)&1][nt] = *(const short8*)(lds + nb[nt] + tapn*XS_ROWB + ckn*32);
            }
            __builtin_amdgcn_s_setprio(1);
            #pragma unroll
            for (int nt = 0; nt < 5; ++nt)
                acc[nt] = __builtin_amdgcn_mfma_f32_32x32x16_bf16(Ar[kt&3], Br[kt&1][nt], acc[nt], 0, 0, 0);
            __builtin_amdgcn_s_setprio(0);
        }
        // store bf16; C layout: col=l31 (time), ch = mt*32 + 8q + 4*l5 + (reg&3)
        #pragma unroll
        for (int nt = 0; nt < 5; ++nt) {
            const int rb = 2 + 32*nt + l31;          // buf row (rs1 <-> t0-18+rb)
            const int t  = t0 - 16 + 32*nt + l31;
            if (rb <= 145) {
                char* dst0 = buf + rb*RS_ROWB + mt*64;
                #pragma unroll
                for (int q = 0; q < 4; ++q) {
                    unsigned long long pk = 0ull;
                    if (t >= 0)
                        pk = (unsigned long long)cvtpk(acc[nt][4*q+0], acc[nt][4*q+1])
                           | ((unsigned long long)cvtpk(acc[nt][4*q+2], acc[nt][4*q+3]) << 32);
                    *(unsigned long long*)(dst0 + q*16 + l5*8) = pk;
                }
            }
        }
    }
    __syncthreads();

    // ---- conv2: rs1 -> rs2 IN-PLACE. Wm=4/Wn=2: mts {2mg,2mg+1}, nt ng?{3,4}:{0,1,2}.
    //      K = 48 kt16. A-ring depth 4, B-ring depth 2 ----
    {
        const int mg = wid >> 1, ng = wid & 1;
        const int mt0 = mg*2;
        const int ntb = ng ? 3 : 0, ncnt = ng ? 2 : 3;
        f32x16 acc[2][3];
        #pragma unroll
        for (int m = 0; m < 2; ++m) {
            f32x4 bq[4];
            #pragma unroll
            for (int q = 0; q < 4; ++q)
                bq[q] = *(const f32x4*)(b_mid + (mt0+m)*32 + q*8 + l5*4);
            #pragma unroll
            for (int nt = 0; nt < 3; ++nt)
                #pragma unroll
                for (int q = 0; q < 4; ++q) {
                    acc[m][nt][4*q+0] = bq[q][0]; acc[m][nt][4*q+1] = bq[q][1];
                    acc[m][nt][4*q+2] = bq[q][2]; acc[m][nt][4*q+3] = bq[q][3];
                }
        }
        int nb[3];
        #pragma unroll
        for (int nt = 0; nt < 3; ++nt)
            nb[nt] = BUF_OFF + (14 + 32*(ntb+nt) + l31)*RS_ROWB + l5*16;

        short8 Ar[4][2];
        short8 Br[2][3];
        #pragma unroll
        for (int k = 0; k < 3; ++k) {
            const int tap = k >> 4, ck = k & 15;
            #pragma unroll
            for (int m = 0; m < 2; ++m)
                Ar[k][m] = ldA(wA2, (tap*8 + mt0+m)*16 + ck, lane);
        }
        #pragma unroll
        for (int nt = 0; nt < 3; ++nt) if (nt < ncnt)
            Br[0][nt] = *(const short8*)(lds + nb[nt]);            // kt=0
        #pragma unroll
        for (int kt = 0; kt < 48; ++kt) {
            if (kt + 3 < 48) {
                const int kn = kt + 3, tapn = kn >> 4, ckn = kn & 15;
                #pragma unroll
                for (int m = 0; m < 2; ++m)
                    Ar[(kt+3)&3][m] = ldA(wA2, (tapn*8 + mt0+m)*16 + ckn, lane);
            }
            if (kt + 1 < 48) {
                const int kn = kt + 1, tapn = kn >> 4, ckn = kn & 15;
                #pragma unroll
                for (int nt = 0; nt < 3; ++nt) if (nt < ncnt)
                    Br[(kt+1)&1][nt] = *(const short8*)(lds + nb[nt] + tapn*RS_ROWB + ckn*32);
            }
            __builtin_amdgcn_s_setprio(1);
            #pragma unroll
            for (int nt = 0; nt < 3; ++nt) if (nt < ncnt) {
                #pragma unroll
                for (int m = 0; m < 2; ++m)
                    acc[m][nt] = __builtin_amdgcn_mfma_f32_32x32x16_bf16(Ar[kt&3][m], Br[kt&1][nt], acc[m][nt], 0, 0, 0);
            }
            __builtin_amdgcn_s_setprio(0);
        }
        __syncthreads();                 // ALL rs1 reads done before in-place overwrite
        #pragma unroll
        for (int nt = 0; nt < 3; ++nt) if (nt < ncnt) {
            const int r2 = 32*(ntb+nt) + l31;        // rs2 row <-> t0-2+r2
            const int t  = t0 - 2 + r2;
            if (r2 <= 129) {
                #pragma unroll
                for (int m = 0; m < 2; ++m) {
                    char* dst0 = buf + r2*RS_ROWB + (mt0+m)*64;
                    #pragma unroll
                    for (int q = 0; q < 4; ++q) {
                        unsigned long long pk = 0ull;
                        if (t >= 0)
                            pk = (unsigned long long)cvtpk(acc[m][nt][4*q+0], acc[m][nt][4*q+1])
                               | ((unsigned long long)cvtpk(acc[m][nt][4*q+2], acc[m][nt][4*q+3]) << 32);
                        *(unsigned long long*)(dst0 + q*16 + l5*8) = pk;
                    }
                }
            }
        }
    }

    // ---- prefetch epilogue x into regs (no LDS dep; hides under conv3) ----
    float xv[16];
    #pragma unroll
    for (int m = 0; m < 16; ++m) {
        const int e = tid + m*512;                   // 8192 = 64c * 128t
        const int c = e >> 7, tl = e & 127;
        xv[m] = x[((size_t)b*C_ + c)*T_ + t0 + tl];
    }
    __syncthreads();

    // ---- conv3: rs2 -> rs3(128, fp32) IN-PLACE. mt=wid&3, ng=wid>>2, nt {2ng,2ng+1}.
    //      A-ring depth 6, B-ring depth 2 ----
    {
        const int mt = wid & 3, ng = wid >> 2;
        const int ntb = ng*2;
        f32x4 bq[4];
        #pragma unroll
        for (int q = 0; q < 4; ++q)
            bq[q] = *(const f32x4*)(b_out + mt*32 + q*8 + l5*4);
        f32x16 acc[2];
        #pragma unroll
        for (int nt = 0; nt < 2; ++nt)
            #pragma unroll
            for (int q = 0; q < 4; ++q) {
                acc[nt][4*q+0] = bq[q][0]; acc[nt][4*q+1] = bq[q][1];
                acc[nt][4*q+2] = bq[q][2]; acc[nt][4*q+3] = bq[q][3];
            }
        int nb[2];
        #pragma unroll
        for (int nt = 0; nt < 2; ++nt)
            nb[nt] = BUF_OFF + (32*(ntb+nt) + l31)*RS_ROWB + l5*16;

        short8 Ar[6];
        short8 Br[2][2];
        #pragma unroll
        for (int k = 0; k < 5; ++k) {
            const int tap = k >> 4, ck = k & 15;
            Ar[k] = ldA(wA3, (tap*4 + mt)*16 + ck, lane);
        }
        #pragma unroll
        for (int nt = 0; nt < 2; ++nt)
            Br[0][nt] = *(const short8*)(lds + nb[nt]);            // kt=0
        #pragma unroll
        for (int kt = 0; kt < 48; ++kt) {
            if (kt + 5 < 48) {
                const int kn = kt + 5, tapn = kn >> 4, ckn = kn & 15;
                Ar[(kt+5)%6] = ldA(wA3, (tapn*4 + mt)*16 + ckn, lane);
            }
            if (kt + 1 < 48) {
                const int kn = kt + 1, tapn = kn >> 4, ckn = kn & 15;
                #pragma unroll
                for (int nt = 0; nt < 2; ++nt)
                    Br[(kt+1)&1][nt] = *(const short8*)(lds + nb[nt] + tapn*RS_ROWB + ckn*32);
            }
            __builtin_amdgcn_s_setprio(1);
            #pragma unroll
            for (int nt = 0; nt < 2; ++nt)
                acc[nt] = __builtin_amdgcn_mfma_f32_32x32x16_bf16(Ar[kt%6], Br[kt&1][nt], acc[nt], 0, 0, 0);
            __builtin_amdgcn_s_setprio(0);
        }
        __syncthreads();                 // ALL rs2 reads done before fp32 overwrite
        #pragma unroll
        for (int nt = 0; nt < 2; ++nt) {
            const int row = 32*(ntb+nt) + l31;       // 0..127, rs3 <-> t0+row
            char* dst0 = buf + row*RS_ROWB + mt*128; // ch byte = ch*4
            #pragma unroll
            for (int q = 0; q < 4; ++q) {
                f32x4 v;
                v[0] = acc[nt][4*q+0]; v[1] = acc[nt][4*q+1];
                v[2] = acc[nt][4*q+2]; v[3] = acc[nt][4*q+3];
                *(f32x4*)(dst0 + q*32 + l5*16) = v;
            }
        }
    }
    __syncthreads();

    // ---- epilogue: z = exp(alpha*tanh(log_s)+beta)*x + t ----
    {
        const float* rs3f = (const float*)buf;       // [128 rows][132 floats]
        #pragma unroll
        for (int m = 0; m < 16; ++m) {
            const int e = tid + m*512;
            const int c = e >> 7, tl = e & 127;
            const float ls = rs3f[tl*132 + c];
            const float tv = rs3f[tl*132 + c + 64];
            const float e2 = __expf(2.f * ls);
            const float th = fmaf(-2.f, __builtin_amdgcn_rcpf(e2 + 1.f), 1.f);
            const float lsv = fmaf(alpha[c], th, beta[c]);
            out[((size_t)b*C_ + c)*T_ + t0 + tl] = fmaf(__expf(lsv), xv[m], tv);
        }
    }
}

extern "C" void kernel_launch(void* const* d_in, const int* in_sizes, int n_in,
                              void* d_out, int out_size, void* d_ws, size_t ws_size,
                              hipStream_t stream) {
    const float* x     = (const float*)d_in[0];
    const float* w_in  = (const float*)d_in[1];
    const float* b_in  = (const float*)d_in[2];
    const float* w_mid = (const float*)d_in[3];
    const float* b_mid = (const float*)d_in[4];
    const float* w_out = (const float*)d_in[5];
    const float* b_out = (const float*)d_in[6];
    const float* alpha = (const float*)d_in[7];
    const float* beta  = (const float*)d_in[8];
    float* out = (float*)d_out;

    if (ws_size < (size_t)AW_TOTAL) return;

    hipLaunchKernelGGL(pack_w, dim3(168), dim3(256), 0, stream,
                       w_in, w_mid, w_out, (unsigned short*)d_ws);
    hipLaunchKernelGGL(arflow_mfma, dim3(T_/TT, B_), dim3(512), 0, stream,
                       x, b_in, b_mid, b_out, alpha, beta, (const char*)d_ws, out);
}